// Round 1
// baseline (624.459 us; speedup 1.0000x reference)
//
#include <hip/hip_runtime.h>
#include <hip/hip_bf16.h>

// ---------------------------------------------------------------------------
// TemporallyCalibratedTransformerLayer  (B=64, N=197, C=768, H=12, Dh=64,
// T_TOK=4, F=3072).  All inputs fp32; internal GEMMs in bf16 MFMA.
// ---------------------------------------------------------------------------

typedef __attribute__((ext_vector_type(8))) short  short8;
typedef __attribute__((ext_vector_type(4))) float  float4v;
typedef __attribute__((ext_vector_type(4))) unsigned short ushort4v;

#define DEV static __device__ __forceinline__

DEV unsigned short f2bf(float f) {
  union { float f; unsigned u; } v; v.f = f;
  unsigned r = v.u + 0x7fffu + ((v.u >> 16) & 1u);   // RNE
  return (unsigned short)(r >> 16);
}
DEV float bf2f(unsigned short h) {
  union { unsigned u; float f; } v; v.u = ((unsigned)h) << 16;
  return v.f;
}

DEV void gld_lds16(const void* g, void* l) {
  __builtin_amdgcn_global_load_lds(
      (const __attribute__((address_space(1))) void*)g,
      (__attribute__((address_space(3))) void*)l, 16, 0, 0);
}

// ---------------------------------------------------------------------------
// fp32 -> bf16 weight conversion
__global__ void wcvt(const float* __restrict__ in, unsigned short* __restrict__ out, int n4) {
  int i = blockIdx.x * 256 + threadIdx.x;
  if (i >= n4) return;
  float4 f = *((const float4*)in + i);
  ushort4v o;
  o[0] = f2bf(f.x); o[1] = f2bf(f.y); o[2] = f2bf(f.z); o[3] = f2bf(f.w);
  *(ushort4v*)(out + (size_t)i * 4) = o;
}

// ---------------------------------------------------------------------------
// LayerNorm over 768, one block per row; writes bf16.
__global__ __launch_bounds__(256) void ln_k(const float* __restrict__ x,
                                            const float* __restrict__ w,
                                            const float* __restrict__ b,
                                            unsigned short* __restrict__ out) {
  int row = blockIdx.x;
  size_t base = (size_t)row * 768;
  int tid = threadIdx.x;
  float v0 = x[base + tid], v1 = x[base + tid + 256], v2 = x[base + tid + 512];
  float s = v0 + v1 + v2;
  float q = v0 * v0 + v1 * v1 + v2 * v2;
  for (int m = 1; m < 64; m <<= 1) { s += __shfl_xor(s, m); q += __shfl_xor(q, m); }
  __shared__ float sh[8];
  int wid = tid >> 6, lane = tid & 63;
  if (lane == 0) { sh[wid] = s; sh[4 + wid] = q; }
  __syncthreads();
  s = sh[0] + sh[1] + sh[2] + sh[3];
  q = sh[4] + sh[5] + sh[6] + sh[7];
  float mean = s * (1.f / 768.f);
  float var  = q * (1.f / 768.f) - mean * mean;
  float rstd = rsqrtf(var + 1e-6f);
  out[base + tid      ] = f2bf((v0 - mean) * rstd * w[tid      ] + b[tid      ]);
  out[base + tid + 256] = f2bf((v1 - mean) * rstd * w[tid + 256] + b[tid + 256]);
  out[base + tid + 512] = f2bf((v2 - mean) * rstd * w[tid + 512] + b[tid + 512]);
}

// ---------------------------------------------------------------------------
// conv1d (k=3, pad=1) over T=4 per-frame CLS tokens, both convq and convk.
// grid (12 cout-chunks of 64, 16 ci-chunks of 48); fp32 atomic partial sums.
__global__ __launch_bounds__(256) void conv_cls(const unsigned short* __restrict__ h,
                                                const float* __restrict__ wq,
                                                const float* __restrict__ wk,
                                                float* __restrict__ cq,
                                                float* __restrict__ ck) {
  __shared__ float gsh[16][6][48];       // [video][t (0,5 zero-pad)][ci]
  int tid = threadIdx.x;
  int cc = blockIdx.x;                   // cout chunk
  int kc = blockIdx.y;                   // ci chunk
  for (int idx = tid; idx < 16 * 2 * 48; idx += 256) {
    int ci = idx % 48; int t = (idx / 48) & 1; int v = idx / 96;
    gsh[v][t * 5][ci] = 0.f;
  }
  for (int idx = tid; idx < 16 * 4 * 48; idx += 256) {
    int ci = idx % 48; int t = (idx / 48) & 3; int v = idx / 192;
    gsh[v][t + 1][ci] = bf2f(h[(size_t)(v * 4 + t) * 197 * 768 + kc * 48 + ci]);
  }
  __syncthreads();
  int cl = tid >> 2, t = tid & 3;
  int cout = cc * 64 + cl;
  const float* wqp = wq + ((size_t)cout * 768 + kc * 48) * 3;
  const float* wkp = wk + ((size_t)cout * 768 + kc * 48) * 3;
  float aq[16] = {}, ak[16] = {};
  for (int ci = 0; ci < 48; ++ci) {
    float q0 = wqp[ci * 3], q1 = wqp[ci * 3 + 1], q2 = wqp[ci * 3 + 2];
    float k0 = wkp[ci * 3], k1 = wkp[ci * 3 + 1], k2 = wkp[ci * 3 + 2];
#pragma unroll
    for (int v = 0; v < 16; ++v) {
      float g0 = gsh[v][t][ci], g1 = gsh[v][t + 1][ci], g2 = gsh[v][t + 2][ci];
      aq[v] += q0 * g0 + q1 * g1 + q2 * g2;
      ak[v] += k0 * g0 + k1 * g1 + k2 * g2;
    }
  }
#pragma unroll
  for (int v = 0; v < 16; ++v) {
    atomicAdd(&cq[(size_t)(v * 4 + t) * 768 + cout], aq[v]);
    atomicAdd(&ck[(size_t)(v * 4 + t) * 768 + cout], ak[v]);
  }
}

// ---------------------------------------------------------------------------
// bf16 MFMA GEMM: C[M,N] = A[M,K] @ W[N,K]^T + bias, epilogue variants.
// 128x128 tile, BK=32, 4 waves each 64x64, global_load_lds(16B) staging,
// XOR-swizzled LDS (linear dest + inverse-swizzled source + swizzled read).
// EPI: 0 = QKV scatter (+cq/+ck), 1 = proj (+res -> f32), 2 = FF1 (+GELU ->
// bf16), 3 = FF2 (+res -> f32 out).
template <int EPI>
__global__ __launch_bounds__(256, 2) void gemm_k(
    const unsigned short* __restrict__ A, const unsigned short* __restrict__ W,
    int M, int N, int K, const float* __restrict__ bias,
    float* __restrict__ out_f, unsigned short* __restrict__ out_h,
    const float* __restrict__ res,
    const float* __restrict__ cq, const float* __restrict__ ck,
    const float* __restrict__ cqb, const float* __restrict__ ckb,
    unsigned short* __restrict__ Qo, unsigned short* __restrict__ Ko,
    unsigned short* __restrict__ Vo) {
  __shared__ unsigned short As[128 * 32];
  __shared__ unsigned short Bs[128 * 32];
  int tid = threadIdx.x;
  int wid = tid >> 6, lane = tid & 63;
  int wr = wid >> 1, wc = wid & 1;
  int cG = lane >> 4, cl = lane & 15;
  long rowBase = (long)blockIdx.x * 128;
  int colBase = blockIdx.y * 128;

  float4v acc[4][4] = {};

  // staging geometry: each thread stages 2x16B per tile
  int off0 = tid * 16, off1 = (256 + tid) * 16;     // byte offsets in 8KB tile
  int r0s = off0 >> 6, r1s = off1 >> 6;             // tile row 0..127
  int s0 = (off0 >> 4) & 3, s1 = (off1 >> 4) & 3;   // 16B slot in row
  int k0s = (s0 ^ ((r0s >> 1) & 3)) * 8;            // inverse-swizzled source chunk (shorts)
  int k1s = (s1 ^ ((r1s >> 1) & 3)) * 8;
  long ar0 = rowBase + r0s; if (ar0 > M - 1) ar0 = M - 1;
  long ar1 = rowBase + r1s; if (ar1 > M - 1) ar1 = M - 1;
  const unsigned short* a0 = A + ar0 * K + k0s;
  const unsigned short* a1 = A + ar1 * K + k1s;
  const unsigned short* w0 = W + (long)(colBase + r0s) * K + k0s;
  const unsigned short* w1 = W + (long)(colBase + r1s) * K + k1s;

  for (int kt = 0; kt < K; kt += 32) {
    __syncthreads();
    gld_lds16(a0 + kt, As + (off0 >> 1));
    gld_lds16(a1 + kt, As + (off1 >> 1));
    gld_lds16(w0 + kt, Bs + (off0 >> 1));
    gld_lds16(w1 + kt, Bs + (off1 >> 1));
    __syncthreads();
    short8 af[4], bfr[4];
#pragma unroll
    for (int fi = 0; fi < 4; ++fi) {
      int r = wr * 64 + fi * 16 + cl;
      int sl = cG ^ ((r >> 1) & 3);
      af[fi] = *(const short8*)(As + r * 32 + sl * 8);
    }
#pragma unroll
    for (int fj = 0; fj < 4; ++fj) {
      int r = wc * 64 + fj * 16 + cl;
      int sl = cG ^ ((r >> 1) & 3);
      bfr[fj] = *(const short8*)(Bs + r * 32 + sl * 8);
    }
#pragma unroll
    for (int fi = 0; fi < 4; ++fi)
#pragma unroll
      for (int fj = 0; fj < 4; ++fj)
        acc[fi][fj] = __builtin_amdgcn_mfma_f32_16x16x32_bf16(af[fi], bfr[fj], acc[fi][fj], 0, 0, 0);
  }

  // epilogue: D col = lane&15, row = 4*(lane>>4)+j
#pragma unroll
  for (int fi = 0; fi < 4; ++fi) {
    long r0 = rowBase + wr * 64 + fi * 16 + 4 * cG;
#pragma unroll
    for (int fj = 0; fj < 4; ++fj) {
      int col = colBase + wc * 64 + fj * 16 + cl;
      float bc = bias[col];
      float4v a = acc[fi][fj];
#pragma unroll
      for (int j = 0; j < 4; ++j) {
        long row = r0 + j;
        if (row >= M) continue;
        float v = a[j] + bc;
        if constexpr (EPI == 0) {
          int sec = col / 768; int ccc = col - sec * 768;
          int bi = (int)(row / 197); int ni = (int)(row - (long)bi * 197);
          size_t oidx = ((size_t)(bi * 12 + (ccc >> 6)) * 197 + ni) * 64 + (ccc & 63);
          if (sec == 0)      { v += cq[bi * 768 + ccc] + cqb[ccc]; Qo[oidx] = f2bf(v); }
          else if (sec == 1) { v += ck[bi * 768 + ccc] + ckb[ccc]; Ko[oidx] = f2bf(v); }
          else               { Vo[oidx] = f2bf(v); }
        } else if constexpr (EPI == 1 || EPI == 3) {
          size_t idx = (size_t)row * N + col;
          out_f[idx] = v + res[idx];
        } else {
          size_t idx = (size_t)row * N + col;
          float g = 0.5f * v * (1.0f + erff(v * 0.70710678118f));
          out_h[idx] = f2bf(g);
        }
      }
    }
  }
}

// ---------------------------------------------------------------------------
// Attention: one block (4 waves) per (b,h).  N=197 padded to 224 in LDS.
// K staged [n][d] XOR-swizzled; V staged transposed [d][n] XOR-swizzled.
__global__ __launch_bounds__(256, 2) void attn_k(const unsigned short* __restrict__ Q,
                                                 const unsigned short* __restrict__ Kg,
                                                 const unsigned short* __restrict__ Vg,
                                                 unsigned short* __restrict__ O) {
  __shared__ unsigned short Ks[224 * 64];   // [n][d], chunk ^= n&7
  __shared__ unsigned short Vt[64 * 224];   // [d][n], n-block ^= (d&7)<<3
  __shared__ unsigned short Ps[4][16 * 40]; // per-wave P chunk [16][32+pad8]
  int g = blockIdx.x;
  int bi = g / 12, hh = g - bi * 12;
  size_t gbase = (size_t)g * 197 * 64;
  int tid = threadIdx.x, wid = tid >> 6, lane = tid & 63;
  int cG = lane >> 4, cl = lane & 15;

  {
    int rr = tid >> 3, ch = tid & 7;
#pragma unroll
    for (int i = 0; i < 7; ++i) {
      int n = rr + 32 * i;
      short8 kv = {0, 0, 0, 0, 0, 0, 0, 0};
      if (n < 197) kv = *(const short8*)(Kg + gbase + (size_t)n * 64 + ch * 8);
      *(short8*)(Ks + n * 64 + (ch ^ (n & 7)) * 8) = kv;
      short8 vv = {0, 0, 0, 0, 0, 0, 0, 0};
      if (n < 197) vv = *(const short8*)(Vg + gbase + (size_t)n * 64 + ch * 8);
#pragma unroll
      for (int j = 0; j < 8; ++j) {
        int dd = ch * 8 + j;
        Vt[dd * 224 + (n ^ ((dd & 7) << 3))] = ((unsigned short*)&vv)[j];
      }
    }
  }
  __syncthreads();

  for (int rt = wid; rt < 13; rt += 4) {
    int nq = rt * 16 + cl; if (nq > 196) nq = 196;
    short8 aq0 = *(const short8*)(Q + gbase + (size_t)nq * 64 + 8 * cG);
    short8 aq1 = *(const short8*)(Q + gbase + (size_t)nq * 64 + 32 + 8 * cG);
    float4v s[14];
#pragma unroll
    for (int ct = 0; ct < 14; ++ct) {
      float4v a = {0.f, 0.f, 0.f, 0.f};
      int np = ct * 16 + cl;
      short8 b0 = *(const short8*)(Ks + np * 64 + ((cG    ) ^ (np & 7)) * 8);
      short8 b1 = *(const short8*)(Ks + np * 64 + ((4 + cG) ^ (np & 7)) * 8);
      a = __builtin_amdgcn_mfma_f32_16x16x32_bf16(aq0, b0, a, 0, 0, 0);
      a = __builtin_amdgcn_mfma_f32_16x16x32_bf16(aq1, b1, a, 0, 0, 0);
      s[ct] = a;
    }
    float mx[4] = {-1e30f, -1e30f, -1e30f, -1e30f};
#pragma unroll
    for (int ct = 0; ct < 14; ++ct) {
      int colv = ct * 16 + cl;
#pragma unroll
      for (int j = 0; j < 4; ++j) {
        float v = (colv < 197) ? s[ct][j] * 0.125f : -1e30f;
        s[ct][j] = v;
        mx[j] = fmaxf(mx[j], v);
      }
    }
#pragma unroll
    for (int m = 1; m < 16; m <<= 1)
#pragma unroll
      for (int j = 0; j < 4; ++j) mx[j] = fmaxf(mx[j], __shfl_xor(mx[j], m));
    float sum[4] = {0.f, 0.f, 0.f, 0.f};
#pragma unroll
    for (int ct = 0; ct < 14; ++ct)
#pragma unroll
      for (int j = 0; j < 4; ++j) {
        float p = __expf(s[ct][j] - mx[j]);
        s[ct][j] = p;
        sum[j] += p;
      }
#pragma unroll
    for (int m = 1; m < 16; m <<= 1)
#pragma unroll
      for (int j = 0; j < 4; ++j) sum[j] += __shfl_xor(sum[j], m);
    float rs[4];
#pragma unroll
    for (int j = 0; j < 4; ++j) rs[j] = 1.0f / sum[j];

    float4v oa[4] = {};
    unsigned short* P = &Ps[wid][0];
#pragma unroll
    for (int ks = 0; ks < 7; ++ks) {
#pragma unroll
      for (int t = 0; t < 2; ++t) {
        int ct = 2 * ks + t;
#pragma unroll
        for (int j = 0; j < 4; ++j)
          P[(4 * cG + j) * 40 + t * 16 + cl] = f2bf(s[ct][j]);
      }
      short8 pa = *(const short8*)(P + cl * 40 + 8 * cG);
#pragma unroll
      for (int dt = 0; dt < 4; ++dt) {
        int dd = dt * 16 + cl;
        short8 bv = *(const short8*)(Vt + dd * 224 + ((ks * 32 + 8 * cG) ^ ((dd & 7) << 3)));
        oa[dt] = __builtin_amdgcn_mfma_f32_16x16x32_bf16(pa, bv, oa[dt], 0, 0, 0);
      }
    }
#pragma unroll
    for (int dt = 0; dt < 4; ++dt)
#pragma unroll
      for (int j = 0; j < 4; ++j) {
        int n2 = rt * 16 + 4 * cG + j;
        if (n2 < 197)
          O[(size_t)(bi * 197 + n2) * 768 + hh * 64 + dt * 16 + cl] = f2bf(oa[dt][j] * rs[j]);
      }
  }
}

// ---------------------------------------------------------------------------
extern "C" void kernel_launch(void* const* d_in, const int* in_sizes, int n_in,
                              void* d_out, int out_size, void* d_ws, size_t ws_size,
                              hipStream_t stream) {
  const float* x     = (const float*)d_in[0];
  const float* ln1w  = (const float*)d_in[1];
  const float* ln1b  = (const float*)d_in[2];
  const float* qkvw  = (const float*)d_in[3];
  const float* qkvb  = (const float*)d_in[4];
  const float* cqw   = (const float*)d_in[5];
  const float* cqb   = (const float*)d_in[6];
  const float* ckw   = (const float*)d_in[7];
  const float* ckb   = (const float*)d_in[8];
  const float* projw = (const float*)d_in[9];
  const float* projb = (const float*)d_in[10];
  const float* ln2w  = (const float*)d_in[11];
  const float* ln2b  = (const float*)d_in[12];
  const float* ff1w  = (const float*)d_in[13];
  const float* ff1b  = (const float*)d_in[14];
  const float* ff2w  = (const float*)d_in[15];
  const float* ff2b  = (const float*)d_in[16];
  float* out = (float*)d_out;

  char* ws = (char*)d_ws;
  const size_t SZ = (size_t)12608 * 768 * 2;          // 19,365,888 B
  unsigned short* Qb  = (unsigned short*)(ws);
  unsigned short* Kb  = (unsigned short*)(ws + SZ);
  unsigned short* Vb  = (unsigned short*)(ws + 2 * SZ);
  unsigned short* Ob  = (unsigned short*)(ws + 3 * SZ);
  unsigned short* ffh = (unsigned short*)(ws);        // overlays Q..O after proj
  unsigned short* hb  = (unsigned short*)(ws + 4 * SZ);
  float* x1 = (float*)(ws + 5 * SZ);
  float* cq = (float*)(ws + 5 * SZ + (size_t)12608 * 768 * 4);
  float* ck = cq + 49152;
  unsigned short* Wqkv  = (unsigned short*)(ck + 49152);
  unsigned short* Wproj = Wqkv + 1769472;
  unsigned short* Wff1  = Wproj + 589824;
  unsigned short* Wff2  = Wff1 + 2359296;

  // weights -> bf16 (inputs restored every timed call, so convert every call)
  wcvt<<<1728, 256, 0, stream>>>(qkvw, Wqkv, 442368);
  wcvt<<<576,  256, 0, stream>>>(projw, Wproj, 147456);
  wcvt<<<2304, 256, 0, stream>>>(ff1w, Wff1, 589824);
  wcvt<<<2304, 256, 0, stream>>>(ff2w, Wff2, 589824);

  // LN1
  ln_k<<<12608, 256, 0, stream>>>(x, ln1w, ln1b, hb);

  // temporal conv on CLS tokens
  hipMemsetAsync(cq, 0, 2 * 49152 * sizeof(float), stream);
  conv_cls<<<dim3(12, 16), 256, 0, stream>>>(hb, cqw, ckw, cq, ck);

  // QKV projection (+cq/+ck fold, scatter to (b*12+h, n, d))
  gemm_k<0><<<dim3(99, 18), 256, 0, stream>>>(hb, Wqkv, 12608, 2304, 768, qkvb,
      nullptr, nullptr, nullptr, cq, ck, cqb, ckb, Qb, Kb, Vb);

  // attention
  attn_k<<<768, 256, 0, stream>>>(Qb, Kb, Vb, Ob);

  // output projection + residual -> x1 (f32)
  gemm_k<1><<<dim3(99, 6), 256, 0, stream>>>(Ob, Wproj, 12608, 768, 768, projb,
      x1, nullptr, x, nullptr, nullptr, nullptr, nullptr, nullptr, nullptr, nullptr);

  // LN2
  ln_k<<<12608, 256, 0, stream>>>(x1, ln2w, ln2b, hb);

  // FF1 + GELU -> bf16
  gemm_k<2><<<dim3(99, 24), 256, 0, stream>>>(hb, Wff1, 12608, 3072, 768, ff1b,
      nullptr, ffh, nullptr, nullptr, nullptr, nullptr, nullptr, nullptr, nullptr, nullptr);

  // FF2 + residual -> out (f32)
  gemm_k<3><<<dim3(99, 6), 256, 0, stream>>>(ffh, Wff2, 12608, 768, 3072, ff2b,
      out, nullptr, x1, nullptr, nullptr, nullptr, nullptr, nullptr, nullptr, nullptr);
}